// Round 2
// baseline (221.394 us; speedup 1.0000x reference)
//
#include <hip/hip_runtime.h>

#define DM   1024
#define LSEQ 1024
#define BATCH 8
#define MROWS (BATCH*LSEQ)   // 8192

typedef __attribute__((ext_vector_type(8))) short  bf16x8;
typedef __attribute__((ext_vector_type(4))) float  f32x4;
typedef __attribute__((ext_vector_type(4))) unsigned short u16x4;
typedef __attribute__((ext_vector_type(8))) unsigned short u16x8;

__device__ inline unsigned short f2bf(float f){
  unsigned u = __builtin_bit_cast(unsigned, f);
  u += 0x7fffu + ((u >> 16) & 1u);          // RNE
  return (unsigned short)(u >> 16);
}

__device__ inline void gload_lds16(const void* g, void* l){
  __builtin_amdgcn_global_load_lds(
      (const __attribute__((address_space(1))) void*)g,
      (__attribute__((address_space(3))) void*)l,
      16, 0, 0);
}

// Stage a 128x32 bf16 tile (src leading dim = 1024) into FRAGMENT-MAJOR LDS:
// layout [nb(8)][kg(4)][fr(16)][8 elems]. global_load_lds writes lane*16B
// linearly, so we permute the GLOBAL source address per lane: row = nb*16+fr,
// col = kg*8. Fragment reads then hit lane*16B contiguous -> 0 bank conflicts.
__device__ inline void stage_gload(const unsigned short* src, int row0, int k0,
                                   unsigned short* lds, int wave, int lane)
{
  int fr = lane & 15, kg = lane >> 4;
  #pragma unroll
  for (int it = 0; it < 2; ++it){
    int nb = it*4 + wave;                 // wave-uniform
    gload_lds16(src + (size_t)(row0 + nb*16 + fr)*1024 + k0 + kg*8,
                lds + nb*512);
  }
}

// one BK=32 step: 4 A-frags, 4 B-frags, 16 MFMAs (fragment-major LDS)
__device__ inline void mma_step(const unsigned short* As, const unsigned short* Bs,
                                int wrb4, int wcb4, int fr, int kg,
                                f32x4 acc[4][4])
{
  bf16x8 av[4], bv[4];
  #pragma unroll
  for (int mi = 0; mi < 4; ++mi)
    av[mi] = *(const bf16x8*)(As + (size_t)(((wrb4 + mi)*4 + kg)*16 + fr)*8);
  #pragma unroll
  for (int ni = 0; ni < 4; ++ni)
    bv[ni] = *(const bf16x8*)(Bs + (size_t)(((wcb4 + ni)*4 + kg)*16 + fr)*8);
  #pragma unroll
  for (int mi = 0; mi < 4; ++mi)
    #pragma unroll
    for (int ni = 0; ni < 4; ++ni)
      acc[mi][ni] = __builtin_amdgcn_mfma_f32_16x16x32_bf16(av[mi], bv[ni], acc[mi][ni], 0, 0, 0);
}

// ---------------- X fp32 -> bf16 bulk convert ----------------
__global__ __launch_bounds__(256) void k_cvt(
    const float* __restrict__ X0, const float* __restrict__ X1, const float* __restrict__ X2,
    unsigned short* __restrict__ Y0, unsigned short* __restrict__ Y1, unsigned short* __restrict__ Y2)
{
  int z = blockIdx.z;
  const float* X = z==0 ? X0 : (z==1 ? X1 : X2);
  unsigned short* Y = z==0 ? Y0 : (z==1 ? Y1 : Y2);
  size_t i = ((size_t)blockIdx.x*256 + threadIdx.x)*8;
  f32x4 a = *(const f32x4*)(X+i);
  f32x4 b = *(const f32x4*)(X+i+4);
  u16x8 o;
  o[0]=f2bf(a[0]); o[1]=f2bf(a[1]); o[2]=f2bf(a[2]); o[3]=f2bf(a[3]);
  o[4]=f2bf(b[0]); o[5]=f2bf(b[1]); o[6]=f2bf(b[2]); o[7]=f2bf(b[3]);
  *(u16x8*)(Y+i) = o;
}

// ---------------- W transpose + convert:  Wt[n][k] = bf16(W[k][n]) ----------------
__global__ __launch_bounds__(256) void k_transpose_w(
    const float* __restrict__ W0, const float* __restrict__ W1, const float* __restrict__ W2,
    unsigned short* __restrict__ T0, unsigned short* __restrict__ T1, unsigned short* __restrict__ T2)
{
  __shared__ unsigned short tile[64*68];
  int z = blockIdx.z;
  const float* W = z==0 ? W0 : (z==1 ? W1 : W2);
  unsigned short* T = z==0 ? T0 : (z==1 ? T1 : T2);
  int n0 = blockIdx.x*64, k0 = blockIdx.y*64;
  int tid = threadIdx.x;
  {
    int r = tid >> 4;                 // 0..15
    int c = (tid & 15) * 4;
    #pragma unroll
    for (int it = 0; it < 4; ++it){
      f32x4 v = *(const f32x4*)(W + (size_t)(k0 + it*16 + r)*DM + n0 + c);
      u16x4 h; h[0]=f2bf(v[0]); h[1]=f2bf(v[1]); h[2]=f2bf(v[2]); h[3]=f2bf(v[3]);
      *(u16x4*)(tile + (it*16 + r)*68 + c) = h;
    }
  }
  __syncthreads();
  {
    int nl = tid >> 2;                // 0..63
    int kc = (tid & 3) * 16;
    u16x8 o;
    #pragma unroll
    for (int j = 0; j < 8; ++j) o[j] = tile[(kc+j)*68 + nl];
    *(u16x8*)(T + (size_t)(n0+nl)*DM + k0 + kc) = o;
    #pragma unroll
    for (int j = 0; j < 8; ++j) o[j] = tile[(kc+8+j)*68 + nl];
    *(u16x8*)(T + (size_t)(n0+nl)*DM + k0 + kc + 8) = o;
  }
}

// ---------------- projection GEMM: out = bf16( Xbf @ W )  ----------------
// z=0 -> q [B][L][D], z=1 -> k [B][L][D], z=2 -> vT [B][D][L] (transposed store)
#define TS 136          // transpose-tile stride (epilogue scratch)

__global__ __launch_bounds__(256) void k_proj(
    const unsigned short* __restrict__ X0, const unsigned short* __restrict__ X1, const unsigned short* __restrict__ X2,
    const unsigned short* __restrict__ W0, const unsigned short* __restrict__ W1, const unsigned short* __restrict__ W2,
    unsigned short* __restrict__ qo, unsigned short* __restrict__ ko, unsigned short* __restrict__ vT)
{
  __shared__ __align__(16) unsigned short smem[128*TS];   // 34816 B; reused for transpose epilogue
  unsigned short* As = smem;              // 128x32 frag-major (8 KB)
  unsigned short* Bs = smem + 128*32;     // 128x32 frag-major (8 KB)
  int z = blockIdx.z;
  const unsigned short* X  = z==0 ? X0 : (z==1 ? X1 : X2);
  const unsigned short* Wt = z==0 ? W0 : (z==1 ? W1 : W2);
  int m0 = blockIdx.y * 128, n0 = blockIdx.x * 128;
  int tid = threadIdx.x;
  int wave = tid >> 6, lane = tid & 63;
  int wrb4 = (wave >> 1) * 4, wcb4 = (wave & 1) * 4;
  int fr = lane & 15, kg = lane >> 4;

  f32x4 acc[4][4] = {};

  for (int kt = 0; kt < DM/32; ++kt){
    int k0 = kt*32;
    stage_gload(X,  m0, k0, As, wave, lane);
    stage_gload(Wt, n0, k0, Bs, wave, lane);
    __syncthreads();
    mma_step(As, Bs, wrb4, wcb4, fr, kg, acc);
    __syncthreads();
  }

  int wrb = wrb4*16, wcb = wcb4*16;
  if (z < 2){
    unsigned short* outp = (z == 0) ? qo : ko;
    #pragma unroll
    for (int mi = 0; mi < 4; ++mi)
      #pragma unroll
      for (int ni = 0; ni < 4; ++ni){
        int r = m0 + wrb + mi*16 + kg*4;
        int c = n0 + wcb + ni*16 + fr;
        #pragma unroll
        for (int i = 0; i < 4; ++i)
          outp[(size_t)(r+i)*DM + c] = f2bf(acc[mi][ni][i]);
      }
  } else {
    unsigned short* Tt = smem;                       // [128 d][TS] holds transposed tile
    #pragma unroll
    for (int mi = 0; mi < 4; ++mi)
      #pragma unroll
      for (int ni = 0; ni < 4; ++ni){
        int rr = wrb + mi*16 + kg*4;                 // local l
        int cc = wcb + ni*16 + fr;                   // local d
        u16x4 t;
        t[0]=f2bf(acc[mi][ni][0]); t[1]=f2bf(acc[mi][ni][1]);
        t[2]=f2bf(acc[mi][ni][2]); t[3]=f2bf(acc[mi][ni][3]);
        *(u16x4*)(Tt + (size_t)cc*TS + rr) = t;
      }
    __syncthreads();
    int b = m0 >> 10, l0 = m0 & 1023;
    int dl = tid >> 1, half = tid & 1;
    unsigned short* dst = vT + ((size_t)b << 20) + (size_t)(n0 + dl)*LSEQ + l0 + half*64;
    const unsigned short* srcT = Tt + (size_t)dl*TS + half*64;
    #pragma unroll
    for (int j = 0; j < 8; ++j)
      *(u16x8*)(dst + j*8) = *(const u16x8*)(srcT + j*8);
  }
}

// ---------------- scores: S[b][q][kk] = (q . k) / 32, causal block-skip ----------------
__global__ __launch_bounds__(256) void k_scores(
    const unsigned short* __restrict__ q, const unsigned short* __restrict__ k,
    float* __restrict__ S)
{
  int b = blockIdx.z, qt = blockIdx.y, kt = blockIdx.x;
  if (kt > qt) return;                               // strictly above diagonal: never read
  __shared__ __align__(16) unsigned short As[128*32];
  __shared__ __align__(16) unsigned short Bs[128*32];
  const unsigned short* qb = q + ((size_t)b << 20);
  const unsigned short* kb = k + ((size_t)b << 20);
  int m0 = qt*128, n0 = kt*128;
  int tid = threadIdx.x, wave = tid >> 6, lane = tid & 63;
  int wrb4 = (wave >> 1)*4, wcb4 = (wave & 1)*4, fr = lane & 15, kg = lane >> 4;
  f32x4 acc[4][4] = {};
  for (int kt2 = 0; kt2 < DM/32; ++kt2){
    int k0 = kt2*32;
    stage_gload(qb, m0, k0, As, wave, lane);
    stage_gload(kb, n0, k0, Bs, wave, lane);
    __syncthreads();
    mma_step(As, Bs, wrb4, wcb4, fr, kg, acc);
    __syncthreads();
  }
  float* Sb = S + ((size_t)b << 20);
  const float scale = 0.03125f;                      // 1/sqrt(1024)
  #pragma unroll
  for (int mi = 0; mi < 4; ++mi)
    #pragma unroll
    for (int ni = 0; ni < 4; ++ni){
      int r = m0 + wrb4*16 + mi*16 + kg*4;
      int c = n0 + wcb4*16 + ni*16 + fr;
      #pragma unroll
      for (int i = 0; i < 4; ++i)
        Sb[(size_t)(r+i)*LSEQ + c] = acc[mi][ni][i] * scale;
    }
}

// ---------------- causal row softmax: P bf16, zeros above diagonal ----------------
__global__ __launch_bounds__(256) void k_softmax(
    const float* __restrict__ S, unsigned short* __restrict__ P)
{
  int gq = blockIdx.x;                                // 0..8191
  int qq = gq & 1023;
  const float* row = S + (size_t)gq * 1024;
  unsigned short* prow = P + (size_t)gq * 1024;
  int tid = threadIdx.x;

  f32x4 v = *(const f32x4*)(row + tid*4);
  float vals[4];
  float m = -1e30f;
  #pragma unroll
  for (int e = 0; e < 4; ++e){
    int idx = tid*4 + e;
    vals[e] = (idx <= qq) ? v[e] : -1e30f;
    m = fmaxf(m, vals[e]);
  }
  #pragma unroll
  for (int off = 32; off >= 1; off >>= 1) m = fmaxf(m, __shfl_xor(m, off));
  __shared__ float redm[4], reds[4];
  if ((tid & 63) == 0) redm[tid >> 6] = m;
  __syncthreads();
  m = fmaxf(fmaxf(redm[0], redm[1]), fmaxf(redm[2], redm[3]));

  float e4[4], s = 0.f;
  #pragma unroll
  for (int e = 0; e < 4; ++e){
    int idx = tid*4 + e;
    e4[e] = (idx <= qq) ? __expf(vals[e] - m) : 0.f;
    s += e4[e];
  }
  #pragma unroll
  for (int off = 32; off >= 1; off >>= 1) s += __shfl_xor(s, off);
  if ((tid & 63) == 0) reds[tid >> 6] = s;
  __syncthreads();
  s = reds[0] + reds[1] + reds[2] + reds[3];
  float inv = 1.f / s;

  u16x4 o;
  #pragma unroll
  for (int e = 0; e < 4; ++e) o[e] = f2bf(e4[e] * inv);
  *(u16x4*)(prow + tid*4) = o;
}

// ---------------- PV: O[b][q][d] = sum_kk P[q][kk] * v[kk][d], K-loop cut at diagonal ----------------
__global__ __launch_bounds__(256) void k_pv(
    const unsigned short* __restrict__ P, const unsigned short* __restrict__ vT,
    float* __restrict__ O)
{
  int b = blockIdx.z, qt = blockIdx.y, dt = blockIdx.x;
  __shared__ __align__(16) unsigned short As[128*32];
  __shared__ __align__(16) unsigned short Bs[128*32];
  const unsigned short* Pb = P  + ((size_t)b << 20);
  const unsigned short* Vb = vT + ((size_t)b << 20);
  int m0 = qt*128, n0 = dt*128;
  int tid = threadIdx.x, wave = tid >> 6, lane = tid & 63;
  int wrb4 = (wave >> 1)*4, wcb4 = (wave & 1)*4, fr = lane & 15, kg = lane >> 4;
  f32x4 acc[4][4] = {};
  int nk = (qt + 1) * 4;                              // kk in [0, (qt+1)*128)
  for (int kt = 0; kt < nk; ++kt){
    int k0 = kt*32;
    stage_gload(Pb, m0, k0, As, wave, lane);
    stage_gload(Vb, n0, k0, Bs, wave, lane);
    __syncthreads();
    mma_step(As, Bs, wrb4, wcb4, fr, kg, acc);
    __syncthreads();
  }
  float* Ob = O + ((size_t)(b*1024 + m0) << 10);
  #pragma unroll
  for (int mi = 0; mi < 4; ++mi)
    #pragma unroll
    for (int ni = 0; ni < 4; ++ni){
      int r = wrb4*16 + mi*16 + kg*4;
      int c = n0 + wcb4*16 + ni*16 + fr;
      #pragma unroll
      for (int i = 0; i < 4; ++i)
        Ob[(size_t)(r+i)*DM + c] = acc[mi][ni][i];
    }
}

extern "C" void kernel_launch(void* const* d_in, const int* in_sizes, int n_in,
                              void* d_out, int out_size, void* d_ws, size_t ws_size,
                              hipStream_t stream)
{
  const float* query = (const float*)d_in[0];
  const float* key   = (const float*)d_in[1];
  const float* value = (const float*)d_in[2];
  const float* Wq    = (const float*)d_in[3];
  const float* Wk    = (const float*)d_in[4];
  const float* Wv    = (const float*)d_in[5];
  float* out = (float*)d_out;

  unsigned short* ws = (unsigned short*)d_ws;
  unsigned short* qb  = ws;                                   // 8192x1024 bf16
  unsigned short* kb  = qb  + (size_t)MROWS*DM;
  unsigned short* vT  = kb  + (size_t)MROWS*DM;               // [B][D][L]
  unsigned short* WqT = vT  + (size_t)MROWS*DM;               // [N][K] bf16
  unsigned short* WkT = WqT + (size_t)DM*DM;
  unsigned short* WvT = WkT + (size_t)DM*DM;
  unsigned short* P   = WvT + (size_t)DM*DM;                  // [B][L][L] bf16

  // Dead-buffer reuse (keeps ws at the proven 70 MB):
  //   Xq,Xk (bf16) live in d_out until k_scores overwrites it with S.
  //   Xv (bf16) lives in the P region until k_softmax overwrites it with P.
  unsigned short* outU = (unsigned short*)d_out;
  unsigned short* Xq = outU;                                  // 8M bf16 = 16 MB
  unsigned short* Xk = outU + (size_t)MROWS*DM;               // 8M bf16 = 16 MB
  unsigned short* Xv = P;                                     // 8M bf16 = 16 MB
  float* S = out;                                             // scores fp32 in d_out

  dim3 blk(256);
  k_transpose_w<<<dim3(16,16,3), blk, 0, stream>>>(Wq, Wk, Wv, WqT, WkT, WvT);
  k_cvt        <<<dim3(4096,1,3), blk, 0, stream>>>(query, key, value, Xq, Xk, Xv);
  k_proj       <<<dim3(8,64,3),  blk, 0, stream>>>(Xq, Xk, Xv, WqT, WkT, WvT, qb, kb, vT);
  k_scores     <<<dim3(8,8,8),   blk, 0, stream>>>(qb, kb, S);
  k_softmax    <<<dim3(8192),    blk, 0, stream>>>(S, P);
  k_pv         <<<dim3(8,8,8),   blk, 0, stream>>>(P, vT, out);
}

// Round 3
// 211.114 us; speedup vs baseline: 1.0487x; 1.0487x over previous
//
#include <hip/hip_runtime.h>

#define DM   1024
#define LSEQ 1024
#define BATCH 8
#define MROWS (BATCH*LSEQ)   // 8192

typedef __attribute__((ext_vector_type(8))) short  bf16x8;
typedef __attribute__((ext_vector_type(4))) float  f32x4;
typedef __attribute__((ext_vector_type(4))) unsigned short u16x4;
typedef __attribute__((ext_vector_type(8))) unsigned short u16x8;

__device__ inline unsigned short f2bf(float f){
  unsigned u = __builtin_bit_cast(unsigned, f);
  u += 0x7fffu + ((u >> 16) & 1u);          // RNE
  return (unsigned short)(u >> 16);
}

__device__ inline void gload_lds16(const void* g, void* l){
  __builtin_amdgcn_global_load_lds(
      (const __attribute__((address_space(1))) void*)g,
      (__attribute__((address_space(3))) void*)l,
      16, 0, 0);
}

// Stage a 128x32 bf16 tile (src leading dim = 1024) into FRAGMENT-MAJOR LDS:
// layout [nb(8)][kg(4)][fr(16)][8 elems]. global_load_lds writes lane*16B
// linearly; we permute the GLOBAL source address per lane so fragment reads
// are lane*16B contiguous -> 0 bank conflicts.
__device__ inline void stage_gload(const unsigned short* src, int row0, int k0,
                                   unsigned short* lds, int wave, int lane)
{
  int fr = lane & 15, kg = lane >> 4;
  #pragma unroll
  for (int it = 0; it < 2; ++it){
    int nb = it*4 + wave;                 // wave-uniform
    gload_lds16(src + (size_t)(row0 + nb*16 + fr)*1024 + k0 + kg*8,
                lds + nb*512);
  }
}

// one BK=32 step: 4 A-frags, 4 B-frags, 16 MFMAs (fragment-major LDS)
__device__ inline void mma_step(const unsigned short* As, const unsigned short* Bs,
                                int wrb4, int wcb4, int fr, int kg,
                                f32x4 acc[4][4])
{
  bf16x8 av[4], bv[4];
  #pragma unroll
  for (int mi = 0; mi < 4; ++mi)
    av[mi] = *(const bf16x8*)(As + (size_t)(((wrb4 + mi)*4 + kg)*16 + fr)*8);
  #pragma unroll
  for (int ni = 0; ni < 4; ++ni)
    bv[ni] = *(const bf16x8*)(Bs + (size_t)(((wcb4 + ni)*4 + kg)*16 + fr)*8);
  #pragma unroll
  for (int mi = 0; mi < 4; ++mi)
    #pragma unroll
    for (int ni = 0; ni < 4; ++ni)
      acc[mi][ni] = __builtin_amdgcn_mfma_f32_16x16x32_bf16(av[mi], bv[ni], acc[mi][ni], 0, 0, 0);
}

// ---------------- X fp32 -> bf16 bulk convert ----------------
__global__ __launch_bounds__(256) void k_cvt(
    const float* __restrict__ X0, const float* __restrict__ X1, const float* __restrict__ X2,
    unsigned short* __restrict__ Y0, unsigned short* __restrict__ Y1, unsigned short* __restrict__ Y2)
{
  int z = blockIdx.z;
  const float* X = z==0 ? X0 : (z==1 ? X1 : X2);
  unsigned short* Y = z==0 ? Y0 : (z==1 ? Y1 : Y2);
  size_t i = ((size_t)blockIdx.x*256 + threadIdx.x)*8;
  f32x4 a = *(const f32x4*)(X+i);
  f32x4 b = *(const f32x4*)(X+i+4);
  u16x8 o;
  o[0]=f2bf(a[0]); o[1]=f2bf(a[1]); o[2]=f2bf(a[2]); o[3]=f2bf(a[3]);
  o[4]=f2bf(b[0]); o[5]=f2bf(b[1]); o[6]=f2bf(b[2]); o[7]=f2bf(b[3]);
  *(u16x8*)(Y+i) = o;
}

// ---------------- W transpose + convert:  Wt[n][k] = bf16(W[k][n]) ----------------
__global__ __launch_bounds__(256) void k_transpose_w(
    const float* __restrict__ W0, const float* __restrict__ W1, const float* __restrict__ W2,
    unsigned short* __restrict__ T0, unsigned short* __restrict__ T1, unsigned short* __restrict__ T2)
{
  __shared__ unsigned short tile[64*68];
  int z = blockIdx.z;
  const float* W = z==0 ? W0 : (z==1 ? W1 : W2);
  unsigned short* T = z==0 ? T0 : (z==1 ? T1 : T2);
  int n0 = blockIdx.x*64, k0 = blockIdx.y*64;
  int tid = threadIdx.x;
  {
    int r = tid >> 4;                 // 0..15
    int c = (tid & 15) * 4;
    #pragma unroll
    for (int it = 0; it < 4; ++it){
      f32x4 v = *(const f32x4*)(W + (size_t)(k0 + it*16 + r)*DM + n0 + c);
      u16x4 h; h[0]=f2bf(v[0]); h[1]=f2bf(v[1]); h[2]=f2bf(v[2]); h[3]=f2bf(v[3]);
      *(u16x4*)(tile + (it*16 + r)*68 + c) = h;
    }
  }
  __syncthreads();
  {
    int nl = tid >> 2;                // 0..63
    int kc = (tid & 3) * 16;
    u16x8 o;
    #pragma unroll
    for (int j = 0; j < 8; ++j) o[j] = tile[(kc+j)*68 + nl];
    *(u16x8*)(T + (size_t)(n0+nl)*DM + k0 + kc) = o;
    #pragma unroll
    for (int j = 0; j < 8; ++j) o[j] = tile[(kc+8+j)*68 + nl];
    *(u16x8*)(T + (size_t)(n0+nl)*DM + k0 + kc + 8) = o;
  }
}

// ---------------- projection GEMM: out = bf16( Xbf @ W ), 2-phase dbuf ----------------
// z=0 -> q [B][L][D], z=1 -> k [B][L][D], z=2 -> vT [B][D][L] (transposed store)
#define TS 136          // transpose-tile stride (epilogue scratch)

__global__ __launch_bounds__(256) void k_proj(
    const unsigned short* __restrict__ X0, const unsigned short* __restrict__ X1, const unsigned short* __restrict__ X2,
    const unsigned short* __restrict__ W0, const unsigned short* __restrict__ W1, const unsigned short* __restrict__ W2,
    unsigned short* __restrict__ qo, unsigned short* __restrict__ ko, unsigned short* __restrict__ vT)
{
  __shared__ __align__(16) unsigned short smem[128*TS];   // 34816 B; dbuf + transpose epilogue
  unsigned short* As0 = smem;
  unsigned short* Bs0 = smem + 4096;
  unsigned short* As1 = smem + 8192;
  unsigned short* Bs1 = smem + 12288;
  int z = blockIdx.z;
  const unsigned short* X  = z==0 ? X0 : (z==1 ? X1 : X2);
  const unsigned short* Wt = z==0 ? W0 : (z==1 ? W1 : W2);
  // XCD-chunked swizzle: 512 blocks/z, 64 per XCD -> each XCD owns 8 M-panels
  int raw = blockIdx.x + 8*blockIdx.y;
  int tile = (raw & 7)*64 + (raw >> 3);
  int n0 = (tile & 7) * 128, m0 = (tile >> 3) * 128;
  int tid = threadIdx.x;
  int wave = tid >> 6, lane = tid & 63;
  int wrb4 = (wave >> 1) * 4, wcb4 = (wave & 1) * 4;
  int fr = lane & 15, kg = lane >> 4;

  f32x4 acc[4][4] = {};

  stage_gload(X,  m0, 0, As0, wave, lane);
  stage_gload(Wt, n0, 0, Bs0, wave, lane);
  __syncthreads();
  for (int kt = 0; kt < 32; kt += 2){
    stage_gload(X,  m0, (kt+1)*32, As1, wave, lane);
    stage_gload(Wt, n0, (kt+1)*32, Bs1, wave, lane);
    mma_step(As0, Bs0, wrb4, wcb4, fr, kg, acc);
    __syncthreads();
    if (kt + 2 < 32){
      stage_gload(X,  m0, (kt+2)*32, As0, wave, lane);
      stage_gload(Wt, n0, (kt+2)*32, Bs0, wave, lane);
    }
    mma_step(As1, Bs1, wrb4, wcb4, fr, kg, acc);
    __syncthreads();
  }

  int wrb = wrb4*16, wcb = wcb4*16;
  if (z < 2){
    unsigned short* outp = (z == 0) ? qo : ko;
    #pragma unroll
    for (int mi = 0; mi < 4; ++mi)
      #pragma unroll
      for (int ni = 0; ni < 4; ++ni){
        int r = m0 + wrb + mi*16 + kg*4;
        int c = n0 + wcb + ni*16 + fr;
        #pragma unroll
        for (int i = 0; i < 4; ++i)
          outp[(size_t)(r+i)*DM + c] = f2bf(acc[mi][ni][i]);
      }
  } else {
    unsigned short* Tt = smem;                       // [128 d][TS] holds transposed tile
    #pragma unroll
    for (int mi = 0; mi < 4; ++mi)
      #pragma unroll
      for (int ni = 0; ni < 4; ++ni){
        int rr = wrb + mi*16 + kg*4;                 // local l
        int cc = wcb + ni*16 + fr;                   // local d
        u16x4 t;
        t[0]=f2bf(acc[mi][ni][0]); t[1]=f2bf(acc[mi][ni][1]);
        t[2]=f2bf(acc[mi][ni][2]); t[3]=f2bf(acc[mi][ni][3]);
        *(u16x4*)(Tt + (size_t)cc*TS + rr) = t;
      }
    __syncthreads();
    int b = m0 >> 10, l0 = m0 & 1023;
    int dl = tid >> 1, half = tid & 1;
    unsigned short* dst = vT + ((size_t)b << 20) + (size_t)(n0 + dl)*LSEQ + l0 + half*64;
    const unsigned short* srcT = Tt + (size_t)dl*TS + half*64;
    #pragma unroll
    for (int j = 0; j < 8; ++j)
      *(u16x8*)(dst + j*8) = *(const u16x8*)(srcT + j*8);
  }
}

// ---------------- scores: S[b][q][kk] = (q . k) / 32, causal block-skip, dbuf ----------------
__global__ __launch_bounds__(256) void k_scores(
    const unsigned short* __restrict__ q, const unsigned short* __restrict__ k,
    float* __restrict__ S)
{
  __shared__ __align__(16) unsigned short smem[16384];
  unsigned short* As0 = smem;
  unsigned short* Bs0 = smem + 4096;
  unsigned short* As1 = smem + 8192;
  unsigned short* Bs1 = smem + 12288;
  int b = blockIdx.z;
  int raw = blockIdx.x + 8*blockIdx.y;
  int tile = (raw & 7)*8 + (raw >> 3);
  int kt = tile & 7, qt = tile >> 3;
  if (kt > qt) return;                               // strictly above diagonal: never computed
  const unsigned short* qb = q + ((size_t)b << 20);
  const unsigned short* kb = k + ((size_t)b << 20);
  int m0 = qt*128, n0 = kt*128;
  int tid = threadIdx.x, wave = tid >> 6, lane = tid & 63;
  int wrb4 = (wave >> 1)*4, wcb4 = (wave & 1)*4, fr = lane & 15, kg = lane >> 4;
  f32x4 acc[4][4] = {};
  stage_gload(qb, m0, 0, As0, wave, lane);
  stage_gload(kb, n0, 0, Bs0, wave, lane);
  __syncthreads();
  for (int kk = 0; kk < 32; kk += 2){
    stage_gload(qb, m0, (kk+1)*32, As1, wave, lane);
    stage_gload(kb, n0, (kk+1)*32, Bs1, wave, lane);
    mma_step(As0, Bs0, wrb4, wcb4, fr, kg, acc);
    __syncthreads();
    if (kk + 2 < 32){
      stage_gload(qb, m0, (kk+2)*32, As0, wave, lane);
      stage_gload(kb, n0, (kk+2)*32, Bs0, wave, lane);
    }
    mma_step(As1, Bs1, wrb4, wcb4, fr, kg, acc);
    __syncthreads();
  }
  float* Sb = S + ((size_t)b << 20);
  const float scale = 0.03125f;                      // 1/sqrt(1024)
  #pragma unroll
  for (int mi = 0; mi < 4; ++mi)
    #pragma unroll
    for (int ni = 0; ni < 4; ++ni){
      int r = m0 + wrb4*16 + mi*16 + kg*4;
      int c = n0 + wcb4*16 + ni*16 + fr;
      #pragma unroll
      for (int i = 0; i < 4; ++i)
        Sb[(size_t)(r+i)*LSEQ + c] = acc[mi][ni][i] * scale;
    }
}

// ---------------- causal row softmax: P bf16, zeros above diagonal ----------------
__global__ __launch_bounds__(256) void k_softmax(
    const float* __restrict__ S, unsigned short* __restrict__ P)
{
  int gq = blockIdx.x;                                // 0..8191
  int qq = gq & 1023;
  const float* row = S + (size_t)gq * 1024;
  unsigned short* prow = P + (size_t)gq * 1024;
  int tid = threadIdx.x;

  f32x4 v = *(const f32x4*)(row + tid*4);
  float vals[4];
  float m = -1e30f;
  #pragma unroll
  for (int e = 0; e < 4; ++e){
    int idx = tid*4 + e;
    vals[e] = (idx <= qq) ? v[e] : -1e30f;
    m = fmaxf(m, vals[e]);
  }
  #pragma unroll
  for (int off = 32; off >= 1; off >>= 1) m = fmaxf(m, __shfl_xor(m, off));
  __shared__ float redm[4], reds[4];
  if ((tid & 63) == 0) redm[tid >> 6] = m;
  __syncthreads();
  m = fmaxf(fmaxf(redm[0], redm[1]), fmaxf(redm[2], redm[3]));

  float e4[4], s = 0.f;
  #pragma unroll
  for (int e = 0; e < 4; ++e){
    int idx = tid*4 + e;
    e4[e] = (idx <= qq) ? __expf(vals[e] - m) : 0.f;
    s += e4[e];
  }
  #pragma unroll
  for (int off = 32; off >= 1; off >>= 1) s += __shfl_xor(s, off);
  if ((tid & 63) == 0) reds[tid >> 6] = s;
  __syncthreads();
  s = reds[0] + reds[1] + reds[2] + reds[3];
  float inv = 1.f / s;

  u16x4 o;
  #pragma unroll
  for (int e = 0; e < 4; ++e) o[e] = f2bf(e4[e] * inv);
  *(u16x4*)(prow + tid*4) = o;
}

// ---------------- PV: O[b][q][d] = sum_kk P[q][kk] * v[kk][d], diag-cut K, dbuf ----------------
__global__ __launch_bounds__(256) void k_pv(
    const unsigned short* __restrict__ P, const unsigned short* __restrict__ vT,
    float* __restrict__ O)
{
  __shared__ __align__(16) unsigned short smem[16384];
  unsigned short* As0 = smem;
  unsigned short* Bs0 = smem + 4096;
  unsigned short* As1 = smem + 8192;
  unsigned short* Bs1 = smem + 12288;
  int b = blockIdx.z;
  int raw = blockIdx.x + 8*blockIdx.y;
  int tile = (raw & 7)*8 + (raw >> 3);
  int dt = tile & 7, qt = tile >> 3;
  const unsigned short* Pb = P  + ((size_t)b << 20);
  const unsigned short* Vb = vT + ((size_t)b << 20);
  int m0 = qt*128, n0 = dt*128;
  int tid = threadIdx.x, wave = tid >> 6, lane = tid & 63;
  int wrb4 = (wave >> 1)*4, wcb4 = (wave & 1)*4, fr = lane & 15, kg = lane >> 4;
  f32x4 acc[4][4] = {};
  int nk = (qt + 1) * 4;                              // kk in [0, (qt+1)*128); always even
  stage_gload(Pb, m0, 0, As0, wave, lane);
  stage_gload(Vb, n0, 0, Bs0, wave, lane);
  __syncthreads();
  for (int kk = 0; kk < nk; kk += 2){
    stage_gload(Pb, m0, (kk+1)*32, As1, wave, lane);
    stage_gload(Vb, n0, (kk+1)*32, Bs1, wave, lane);
    mma_step(As0, Bs0, wrb4, wcb4, fr, kg, acc);
    __syncthreads();
    if (kk + 2 < nk){
      stage_gload(Pb, m0, (kk+2)*32, As0, wave, lane);
      stage_gload(Vb, n0, (kk+2)*32, Bs0, wave, lane);
    }
    mma_step(As1, Bs1, wrb4, wcb4, fr, kg, acc);
    __syncthreads();
  }
  float* Ob = O + ((size_t)(b*1024 + m0) << 10);
  #pragma unroll
  for (int mi = 0; mi < 4; ++mi)
    #pragma unroll
    for (int ni = 0; ni < 4; ++ni){
      int r = wrb4*16 + mi*16 + kg*4;
      int c = n0 + wcb4*16 + ni*16 + fr;
      #pragma unroll
      for (int i = 0; i < 4; ++i)
        Ob[(size_t)(r+i)*DM + c] = acc[mi][ni][i];
    }
}

extern "C" void kernel_launch(void* const* d_in, const int* in_sizes, int n_in,
                              void* d_out, int out_size, void* d_ws, size_t ws_size,
                              hipStream_t stream)
{
  const float* query = (const float*)d_in[0];
  const float* key   = (const float*)d_in[1];
  const float* value = (const float*)d_in[2];
  const float* Wq    = (const float*)d_in[3];
  const float* Wk    = (const float*)d_in[4];
  const float* Wv    = (const float*)d_in[5];
  float* out = (float*)d_out;

  unsigned short* ws = (unsigned short*)d_ws;
  unsigned short* qb  = ws;                                   // 8192x1024 bf16
  unsigned short* kb  = qb  + (size_t)MROWS*DM;
  unsigned short* vT  = kb  + (size_t)MROWS*DM;               // [B][D][L]
  unsigned short* WqT = vT  + (size_t)MROWS*DM;               // [N][K] bf16
  unsigned short* WkT = WqT + (size_t)DM*DM;
  unsigned short* WvT = WkT + (size_t)DM*DM;
  unsigned short* P   = WvT + (size_t)DM*DM;                  // [B][L][L] bf16

  // Dead-buffer reuse:
  //   Xq,Xk (bf16) live in d_out until k_scores overwrites it with S.
  //   Xv (bf16) lives in the P region until k_softmax overwrites it with P.
  unsigned short* outU = (unsigned short*)d_out;
  unsigned short* Xq = outU;                                  // 8M bf16 = 16 MB
  unsigned short* Xk = outU + (size_t)MROWS*DM;               // 8M bf16 = 16 MB
  unsigned short* Xv = P;                                     // 8M bf16 = 16 MB
  float* S = out;                                             // scores fp32 in d_out

  dim3 blk(256);
  k_transpose_w<<<dim3(16,16,3), blk, 0, stream>>>(Wq, Wk, Wv, WqT, WkT, WvT);
  k_cvt        <<<dim3(4096,1,3), blk, 0, stream>>>(query, key, value, Xq, Xk, Xv);
  k_proj       <<<dim3(8,64,3),  blk, 0, stream>>>(Xq, Xk, Xv, WqT, WkT, WvT, qb, kb, vT);
  k_scores     <<<dim3(8,8,8),   blk, 0, stream>>>(qb, kb, S);
  k_softmax    <<<dim3(8192),    blk, 0, stream>>>(S, P);
  k_pv         <<<dim3(8,8,8),   blk, 0, stream>>>(P, vT, out);
}

// Round 4
// 206.658 us; speedup vs baseline: 1.0713x; 1.0216x over previous
//
#include <hip/hip_runtime.h>

#define DM   1024
#define LSEQ 1024
#define BATCH 8
#define MROWS (BATCH*LSEQ)   // 8192

typedef __attribute__((ext_vector_type(8))) short  bf16x8;
typedef __attribute__((ext_vector_type(4))) float  f32x4;
typedef __attribute__((ext_vector_type(4))) unsigned short u16x4;
typedef __attribute__((ext_vector_type(8))) unsigned short u16x8;

__device__ inline unsigned short f2bf(float f){
  unsigned u = __builtin_bit_cast(unsigned, f);
  u += 0x7fffu + ((u >> 16) & 1u);          // RNE
  return (unsigned short)(u >> 16);
}

__device__ inline void gload_lds16(const void* g, void* l){
  __builtin_amdgcn_global_load_lds(
      (const __attribute__((address_space(1))) void*)g,
      (__attribute__((address_space(3))) void*)l,
      16, 0, 0);
}

// Stage a 128x32 bf16 tile (src leading dim = 1024) into FRAGMENT-MAJOR LDS:
// layout [nb(8)][kg(4)][fr(16)][8 elems]. global_load_lds writes lane*16B
// linearly; we permute the GLOBAL source address per lane so fragment reads
// are lane*16B contiguous -> 0 bank conflicts. 2 VMEM insts/thread per call.
__device__ inline void stage_gload(const unsigned short* src, int row0, int k0,
                                   unsigned short* lds, int wave, int lane)
{
  int fr = lane & 15, kg = lane >> 4;
  #pragma unroll
  for (int it = 0; it < 2; ++it){
    int nb = it*4 + wave;                 // wave-uniform
    gload_lds16(src + (size_t)(row0 + nb*16 + fr)*1024 + k0 + kg*8,
                lds + nb*512);
  }
}

// one BK=32 step: 4 A-frags, 4 B-frags, 16 MFMAs (fragment-major LDS)
__device__ inline void mma_step(const unsigned short* As, const unsigned short* Bs,
                                int wrb4, int wcb4, int fr, int kg,
                                f32x4 acc[4][4])
{
  bf16x8 av[4], bv[4];
  #pragma unroll
  for (int mi = 0; mi < 4; ++mi)
    av[mi] = *(const bf16x8*)(As + (size_t)(((wrb4 + mi)*4 + kg)*16 + fr)*8);
  #pragma unroll
  for (int ni = 0; ni < 4; ++ni)
    bv[ni] = *(const bf16x8*)(Bs + (size_t)(((wcb4 + ni)*4 + kg)*16 + fr)*8);
  #pragma unroll
  for (int mi = 0; mi < 4; ++mi)
    #pragma unroll
    for (int ni = 0; ni < 4; ++ni)
      acc[mi][ni] = __builtin_amdgcn_mfma_f32_16x16x32_bf16(av[mi], bv[ni], acc[mi][ni], 0, 0, 0);
}

// Ring-buffer GEMM main loop: depth-3 LDS ring (slots of 16 KB: A 4096 + B 4096
// shorts), ONE raw s_barrier per K-step, counted vmcnt (never 0 mid-loop).
// Slot written at iter kt is (kt+2)%3 == (kt-1)%3: its readers finished
// mma(kt-1) before barrier(kt); the stage is issued after barrier(kt) -> safe.
__device__ inline void gemm_ring(const unsigned short* __restrict__ A, int m0,
                                 const unsigned short* __restrict__ B, int n0,
                                 unsigned short* smem, int nk,
                                 int wave, int lane,
                                 int wrb4, int wcb4, int fr, int kg,
                                 f32x4 acc[4][4])
{
  stage_gload(A, m0, 0,  smem,        wave, lane);
  stage_gload(B, n0, 0,  smem + 4096, wave, lane);
  stage_gload(A, m0, 32, smem + 8192, wave, lane);
  stage_gload(B, n0, 32, smem + 8192 + 4096, wave, lane);
  for (int kt = 0; kt < nk; ++kt){
    // wait: outstanding = tile kt (4 loads) + tile kt+1 (4 loads, if staged).
    if (kt + 1 < nk) asm volatile("s_waitcnt vmcnt(4)\n\ts_barrier" ::: "memory");
    else             asm volatile("s_waitcnt vmcnt(0)\n\ts_barrier" ::: "memory");
    unsigned short* buf = smem + (unsigned)(kt % 3) * 8192;
    mma_step(buf, buf + 4096, wrb4, wcb4, fr, kg, acc);
    if (kt + 2 < nk){
      unsigned short* nb = smem + (unsigned)((kt + 2) % 3) * 8192;
      stage_gload(A, m0, (kt+2)*32, nb,        wave, lane);
      stage_gload(B, n0, (kt+2)*32, nb + 4096, wave, lane);
    }
  }
}

// ---------------- X fp32 -> bf16 bulk convert ----------------
__global__ __launch_bounds__(256) void k_cvt(
    const float* __restrict__ X0, const float* __restrict__ X1, const float* __restrict__ X2,
    unsigned short* __restrict__ Y0, unsigned short* __restrict__ Y1, unsigned short* __restrict__ Y2)
{
  int z = blockIdx.z;
  const float* X = z==0 ? X0 : (z==1 ? X1 : X2);
  unsigned short* Y = z==0 ? Y0 : (z==1 ? Y1 : Y2);
  size_t i = ((size_t)blockIdx.x*256 + threadIdx.x)*8;
  f32x4 a = *(const f32x4*)(X+i);
  f32x4 b = *(const f32x4*)(X+i+4);
  u16x8 o;
  o[0]=f2bf(a[0]); o[1]=f2bf(a[1]); o[2]=f2bf(a[2]); o[3]=f2bf(a[3]);
  o[4]=f2bf(b[0]); o[5]=f2bf(b[1]); o[6]=f2bf(b[2]); o[7]=f2bf(b[3]);
  *(u16x8*)(Y+i) = o;
}

// ---------------- W transpose + convert:  Wt[n][k] = bf16(W[k][n]) ----------------
__global__ __launch_bounds__(256) void k_transpose_w(
    const float* __restrict__ W0, const float* __restrict__ W1, const float* __restrict__ W2,
    unsigned short* __restrict__ T0, unsigned short* __restrict__ T1, unsigned short* __restrict__ T2)
{
  __shared__ unsigned short tile[64*68];
  int z = blockIdx.z;
  const float* W = z==0 ? W0 : (z==1 ? W1 : W2);
  unsigned short* T = z==0 ? T0 : (z==1 ? T1 : T2);
  int n0 = blockIdx.x*64, k0 = blockIdx.y*64;
  int tid = threadIdx.x;
  {
    int r = tid >> 4;                 // 0..15
    int c = (tid & 15) * 4;
    #pragma unroll
    for (int it = 0; it < 4; ++it){
      f32x4 v = *(const f32x4*)(W + (size_t)(k0 + it*16 + r)*DM + n0 + c);
      u16x4 h; h[0]=f2bf(v[0]); h[1]=f2bf(v[1]); h[2]=f2bf(v[2]); h[3]=f2bf(v[3]);
      *(u16x4*)(tile + (it*16 + r)*68 + c) = h;
    }
  }
  __syncthreads();
  {
    int nl = tid >> 2;                // 0..63
    int kc = (tid & 3) * 16;
    u16x8 o;
    #pragma unroll
    for (int j = 0; j < 8; ++j) o[j] = tile[(kc+j)*68 + nl];
    *(u16x8*)(T + (size_t)(n0+nl)*DM + k0 + kc) = o;
    #pragma unroll
    for (int j = 0; j < 8; ++j) o[j] = tile[(kc+8+j)*68 + nl];
    *(u16x8*)(T + (size_t)(n0+nl)*DM + k0 + kc + 8) = o;
  }
}

// ---------------- projection GEMM: out = bf16( Xbf @ W ), ring pipeline ----------------
// z=0 -> q [B][L][D], z=1 -> k [B][L][D], z=2 -> vT [B][D][L] (transposed store)
#define TS 136          // transpose-tile stride (epilogue scratch)

__global__ __launch_bounds__(256) void k_proj(
    const unsigned short* __restrict__ X0, const unsigned short* __restrict__ X1, const unsigned short* __restrict__ X2,
    const unsigned short* __restrict__ W0, const unsigned short* __restrict__ W1, const unsigned short* __restrict__ W2,
    unsigned short* __restrict__ qo, unsigned short* __restrict__ ko, unsigned short* __restrict__ vT)
{
  __shared__ __align__(16) unsigned short smem[24576];    // 48 KB: 3 ring slots; epilogue scratch
  int z = blockIdx.z;
  const unsigned short* X  = z==0 ? X0 : (z==1 ? X1 : X2);
  const unsigned short* Wt = z==0 ? W0 : (z==1 ? W1 : W2);
  // XCD-chunked swizzle: 512 blocks/z, 64 per XCD -> each XCD owns 8 M-panels
  int raw = blockIdx.x + 8*blockIdx.y;
  int tile = (raw & 7)*64 + (raw >> 3);
  int n0 = (tile & 7) * 128, m0 = (tile >> 3) * 128;
  int tid = threadIdx.x;
  int wave = tid >> 6, lane = tid & 63;
  int wrb4 = (wave >> 1) * 4, wcb4 = (wave & 1) * 4;
  int fr = lane & 15, kg = lane >> 4;

  f32x4 acc[4][4] = {};
  gemm_ring(X, m0, Wt, n0, smem, 32, wave, lane, wrb4, wcb4, fr, kg, acc);

  int wrb = wrb4*16, wcb = wcb4*16;
  if (z < 2){
    unsigned short* outp = (z == 0) ? qo : ko;
    #pragma unroll
    for (int mi = 0; mi < 4; ++mi)
      #pragma unroll
      for (int ni = 0; ni < 4; ++ni){
        int r = m0 + wrb + mi*16 + kg*4;
        int c = n0 + wcb + ni*16 + fr;
        #pragma unroll
        for (int i = 0; i < 4; ++i)
          outp[(size_t)(r+i)*DM + c] = f2bf(acc[mi][ni][i]);
      }
  } else {
    __syncthreads();                                 // all mma reads done; reuse smem
    unsigned short* Tt = smem;                       // [128 d][TS] holds transposed tile
    #pragma unroll
    for (int mi = 0; mi < 4; ++mi)
      #pragma unroll
      for (int ni = 0; ni < 4; ++ni){
        int rr = wrb + mi*16 + kg*4;                 // local l
        int cc = wcb + ni*16 + fr;                   // local d
        u16x4 t;
        t[0]=f2bf(acc[mi][ni][0]); t[1]=f2bf(acc[mi][ni][1]);
        t[2]=f2bf(acc[mi][ni][2]); t[3]=f2bf(acc[mi][ni][3]);
        *(u16x4*)(Tt + (size_t)cc*TS + rr) = t;
      }
    __syncthreads();
    int b = m0 >> 10, l0 = m0 & 1023;
    int dl = tid >> 1, half = tid & 1;
    unsigned short* dst = vT + ((size_t)b << 20) + (size_t)(n0 + dl)*LSEQ + l0 + half*64;
    const unsigned short* srcT = Tt + (size_t)dl*TS + half*64;
    #pragma unroll
    for (int j = 0; j < 8; ++j)
      *(u16x8*)(dst + j*8) = *(const u16x8*)(srcT + j*8);
  }
}

// ---------------- scores: S[b][q][kk] = (q . k) / 32, causal block-skip, ring ----------------
__global__ __launch_bounds__(256) void k_scores(
    const unsigned short* __restrict__ q, const unsigned short* __restrict__ k,
    float* __restrict__ S)
{
  __shared__ __align__(16) unsigned short smem[24576];
  int b = blockIdx.z;
  int raw = blockIdx.x + 8*blockIdx.y;
  int tile = (raw & 7)*8 + (raw >> 3);
  int kt = tile & 7, qt = tile >> 3;
  if (kt > qt) return;                               // block-uniform exit (no barriers hit)
  const unsigned short* qb = q + ((size_t)b << 20);
  const unsigned short* kb = k + ((size_t)b << 20);
  int m0 = qt*128, n0 = kt*128;
  int tid = threadIdx.x, wave = tid >> 6, lane = tid & 63;
  int wrb4 = (wave >> 1)*4, wcb4 = (wave & 1)*4, fr = lane & 15, kg = lane >> 4;
  f32x4 acc[4][4] = {};
  gemm_ring(qb, m0, kb, n0, smem, 32, wave, lane, wrb4, wcb4, fr, kg, acc);

  float* Sb = S + ((size_t)b << 20);
  const float scale = 0.03125f;                      // 1/sqrt(1024)
  #pragma unroll
  for (int mi = 0; mi < 4; ++mi)
    #pragma unroll
    for (int ni = 0; ni < 4; ++ni){
      int r = m0 + wrb4*16 + mi*16 + kg*4;
      int c = n0 + wcb4*16 + ni*16 + fr;
      #pragma unroll
      for (int i = 0; i < 4; ++i)
        Sb[(size_t)(r+i)*LSEQ + c] = acc[mi][ni][i] * scale;
    }
}

// ---------------- causal row softmax: P bf16, zeros above diagonal ----------------
__global__ __launch_bounds__(256) void k_softmax(
    const float* __restrict__ S, unsigned short* __restrict__ P)
{
  int gq = blockIdx.x;                                // 0..8191
  int qq = gq & 1023;
  const float* row = S + (size_t)gq * 1024;
  unsigned short* prow = P + (size_t)gq * 1024;
  int tid = threadIdx.x;

  f32x4 v = *(const f32x4*)(row + tid*4);
  float vals[4];
  float m = -1e30f;
  #pragma unroll
  for (int e = 0; e < 4; ++e){
    int idx = tid*4 + e;
    vals[e] = (idx <= qq) ? v[e] : -1e30f;
    m = fmaxf(m, vals[e]);
  }
  #pragma unroll
  for (int off = 32; off >= 1; off >>= 1) m = fmaxf(m, __shfl_xor(m, off));
  __shared__ float redm[4], reds[4];
  if ((tid & 63) == 0) redm[tid >> 6] = m;
  __syncthreads();
  m = fmaxf(fmaxf(redm[0], redm[1]), fmaxf(redm[2], redm[3]));

  float e4[4], s = 0.f;
  #pragma unroll
  for (int e = 0; e < 4; ++e){
    int idx = tid*4 + e;
    e4[e] = (idx <= qq) ? __expf(vals[e] - m) : 0.f;
    s += e4[e];
  }
  #pragma unroll
  for (int off = 32; off >= 1; off >>= 1) s += __shfl_xor(s, off);
  if ((tid & 63) == 0) reds[tid >> 6] = s;
  __syncthreads();
  s = reds[0] + reds[1] + reds[2] + reds[3];
  float inv = 1.f / s;

  u16x4 o;
  #pragma unroll
  for (int e = 0; e < 4; ++e) o[e] = f2bf(e4[e] * inv);
  *(u16x4*)(prow + tid*4) = o;
}

// ---------------- PV: O[b][q][d] = sum_kk P[q][kk] * v[kk][d], diag-cut K, ring ----------------
__global__ __launch_bounds__(256) void k_pv(
    const unsigned short* __restrict__ P, const unsigned short* __restrict__ vT,
    float* __restrict__ O)
{
  __shared__ __align__(16) unsigned short smem[24576];
  int b = blockIdx.z;
  int raw = blockIdx.x + 8*blockIdx.y;
  int tile = (raw & 7)*8 + (raw >> 3);
  int dt = tile & 7, qt = tile >> 3;
  const unsigned short* Pb = P  + ((size_t)b << 20);
  const unsigned short* Vb = vT + ((size_t)b << 20);
  int m0 = qt*128, n0 = dt*128;
  int tid = threadIdx.x, wave = tid >> 6, lane = tid & 63;
  int wrb4 = (wave >> 1)*4, wcb4 = (wave & 1)*4, fr = lane & 15, kg = lane >> 4;
  f32x4 acc[4][4] = {};
  int nk = (qt + 1) * 4;                              // kk in [0, (qt+1)*128); >= 4
  gemm_ring(Pb, m0, Vb, n0, smem, nk, wave, lane, wrb4, wcb4, fr, kg, acc);

  float* Ob = O + ((size_t)(b*1024 + m0) << 10);
  #pragma unroll
  for (int mi = 0; mi < 4; ++mi)
    #pragma unroll
    for (int ni = 0; ni < 4; ++ni){
      int r = wrb4*16 + mi*16 + kg*4;
      int c = n0 + wcb4*16 + ni*16 + fr;
      #pragma unroll
      for (int i = 0; i < 4; ++i)
        Ob[(size_t)(r+i)*DM + c] = acc[mi][ni][i];
    }
}

extern "C" void kernel_launch(void* const* d_in, const int* in_sizes, int n_in,
                              void* d_out, int out_size, void* d_ws, size_t ws_size,
                              hipStream_t stream)
{
  const float* query = (const float*)d_in[0];
  const float* key   = (const float*)d_in[1];
  const float* value = (const float*)d_in[2];
  const float* Wq    = (const float*)d_in[3];
  const float* Wk    = (const float*)d_in[4];
  const float* Wv    = (const float*)d_in[5];
  float* out = (float*)d_out;

  unsigned short* ws = (unsigned short*)d_ws;
  unsigned short* qb  = ws;                                   // 8192x1024 bf16
  unsigned short* kb  = qb  + (size_t)MROWS*DM;
  unsigned short* vT  = kb  + (size_t)MROWS*DM;               // [B][D][L]
  unsigned short* WqT = vT  + (size_t)MROWS*DM;               // [N][K] bf16
  unsigned short* WkT = WqT + (size_t)DM*DM;
  unsigned short* WvT = WkT + (size_t)DM*DM;
  unsigned short* P   = WvT + (size_t)DM*DM;                  // [B][L][L] bf16

  // Dead-buffer reuse:
  //   Xq,Xk (bf16) live in d_out until k_scores overwrites it with S.
  //   Xv (bf16) lives in the P region until k_softmax overwrites it with P.
  unsigned short* outU = (unsigned short*)d_out;
  unsigned short* Xq = outU;                                  // 8M bf16 = 16 MB
  unsigned short* Xk = outU + (size_t)MROWS*DM;               // 8M bf16 = 16 MB
  unsigned short* Xv = P;                                     // 8M bf16 = 16 MB
  float* S = out;                                             // scores fp32 in d_out

  dim3 blk(256);
  k_transpose_w<<<dim3(16,16,3), blk, 0, stream>>>(Wq, Wk, Wv, WqT, WkT, WvT);
  k_cvt        <<<dim3(4096,1,3), blk, 0, stream>>>(query, key, value, Xq, Xk, Xv);
  k_proj       <<<dim3(8,64,3),  blk, 0, stream>>>(Xq, Xk, Xv, WqT, WkT, WvT, qb, kb, vT);
  k_scores     <<<dim3(8,8,8),   blk, 0, stream>>>(qb, kb, S);
  k_softmax    <<<dim3(8192),    blk, 0, stream>>>(S, P);
  k_pv         <<<dim3(8,8,8),   blk, 0, stream>>>(P, vT, out);
}